// Round 1
// baseline (2972.174 us; speedup 1.0000x reference)
//
#include <hip/hip_runtime.h>
#include <hip/hip_bf16.h>
#include <cstdint>
#include <cstddef>

// ---------------------------------------------------------------------------
// MiniGPT forward on MI355X (gfx950).  Round 0: correctness-first baseline.
//   bf16 MFMA GEMMs (16x16x32), f32 residual stream / softmax / LN.
// Shapes fixed by the problem: B=1 S=2048 D=1024 Dff=4096 L=6 H=16 dk=64 V=32000
// ---------------------------------------------------------------------------

typedef __attribute__((ext_vector_type(4))) float  f32x4;
typedef __attribute__((ext_vector_type(8))) __bf16 bf16x8;
typedef __attribute__((ext_vector_type(4))) __bf16 bf16x4;

#define S_LEN 2048
#define DMODEL 1024
#define DFF 4096
#define NLAYER 6
#define NHEAD 16
#define DK 64
#define VOCAB 32000

// ---- async global->LDS (16B per lane, wave-uniform LDS base) --------------
__device__ __forceinline__ void gload_lds16(const void* g, void* l) {
    __builtin_amdgcn_global_load_lds(
        (__attribute__((address_space(1))) void*)(void*)(g),
        (__attribute__((address_space(3))) void*)(l), 16, 0, 0);
}

// ---------------------------------------------------------------------------
// transpose + f32->bf16:  in[K][N] (f32, row-major) -> out[N][K] (bf16)
// K, N divisible by 32.  block (32,8), grid (N/32, K/32)
// ---------------------------------------------------------------------------
__global__ __launch_bounds__(256) void transpose_cvt(
    const float* __restrict__ in, __bf16* __restrict__ out, int K, int N) {
    __shared__ float tile[32][33];
    const int n0 = blockIdx.x * 32, k0 = blockIdx.y * 32;
    const int tx = threadIdx.x, ty = threadIdx.y;
#pragma unroll
    for (int j = 0; j < 32; j += 8)
        tile[ty + j][tx] = in[(size_t)(k0 + ty + j) * N + (n0 + tx)];
    __syncthreads();
#pragma unroll
    for (int j = 0; j < 32; j += 8)
        out[(size_t)(n0 + ty + j) * K + (k0 + tx)] = (__bf16)tile[tx][ty + j];
}

// ---- plain f32 -> bf16 convert (4 elems/thread) ---------------------------
__global__ __launch_bounds__(256) void cvt_bf16(
    const float* __restrict__ in, __bf16* __restrict__ out, long n4) {
    long i = (long)blockIdx.x * 256 + threadIdx.x;
    if (i >= n4) return;
    float4 v = ((const float4*)in)[i];
    bf16x4 o = {(__bf16)v.x, (__bf16)v.y, (__bf16)v.z, (__bf16)v.w};
    ((bf16x4*)out)[i] = o;
}

// ---- embedding: x[s][d] = tok_emb[tokens[s]][d] + pos_emb[s][d] (f32) -----
__global__ __launch_bounds__(256) void embed_kernel(
    const int* __restrict__ tokens, const float* __restrict__ te,
    const float* __restrict__ pe, float* __restrict__ x) {
    const int s = blockIdx.x, t = threadIdx.x;
    const int tok = tokens[s];
    float4 a = ((const float4*)(te + (size_t)tok * DMODEL))[t];
    float4 p = ((const float4*)(pe + (size_t)s * DMODEL))[t];
    float4 r = {a.x + p.x, a.y + p.y, a.z + p.z, a.w + p.w};
    ((float4*)(x + (size_t)s * DMODEL))[t] = r;
}

// ---- LayerNorm row kernel: f32 in -> bf16 out (grid = rows, block 256) ----
__global__ __launch_bounds__(256) void ln_kernel(
    const float* __restrict__ x, const float* __restrict__ g,
    const float* __restrict__ b, __bf16* __restrict__ out) {
    const int row = blockIdx.x, t = threadIdx.x;
    float4 v = ((const float4*)(x + (size_t)row * DMODEL))[t];
    float s  = v.x + v.y + v.z + v.w;
    float s2 = v.x * v.x + v.y * v.y + v.z * v.z + v.w * v.w;
#pragma unroll
    for (int off = 1; off < 64; off <<= 1) {
        s  += __shfl_xor(s, off);
        s2 += __shfl_xor(s2, off);
    }
    __shared__ float ss[4], ss2[4];
    const int wave = t >> 6;
    if ((t & 63) == 0) { ss[wave] = s; ss2[wave] = s2; }
    __syncthreads();
    s  = ss[0] + ss[1] + ss[2] + ss[3];
    s2 = ss2[0] + ss2[1] + ss2[2] + ss2[3];
    const float mu  = s * (1.0f / DMODEL);
    const float var = s2 * (1.0f / DMODEL) - mu * mu;
    const float rstd = rsqrtf(var + 1e-5f);
    float4 gg = ((const float4*)g)[t];
    float4 bb = ((const float4*)b)[t];
    __bf16* o = out + (size_t)row * DMODEL + t * 4;
    o[0] = (__bf16)((v.x - mu) * rstd * gg.x + bb.x);
    o[1] = (__bf16)((v.y - mu) * rstd * gg.y + bb.y);
    o[2] = (__bf16)((v.z - mu) * rstd * gg.z + bb.z);
    o[3] = (__bf16)((v.w - mu) * rstd * gg.w + bb.w);
}

// ---------------------------------------------------------------------------
// GEMM:  C(M,N) = A(M,K) * B(K,N), A bf16 row-major, BT bf16 (N,K) row-major.
// Tile 128x128, BK=32, 256 threads (4 waves, 2x2 of 64x64 wave tiles).
// MODE 0: QKV split epilogue   (N=3072; q scaled by 0.125; v stored [h][d][s])
// MODE 1: residual             fout[row,col] += acc + bias[col]    (f32 io)
// MODE 2: exact GELU -> bf16   bfout = gelu(acc + bias)
// MODE 3: plain f32 store      fout = acc
// ---------------------------------------------------------------------------
template <int MODE>
__global__ __launch_bounds__(256) void gemm_kernel(
    const __bf16* __restrict__ A, const __bf16* __restrict__ BT,
    int M, int N, int K,
    const float* __restrict__ bias,
    float* __restrict__ fout,
    __bf16* __restrict__ bfout,
    __bf16* __restrict__ qb, __bf16* __restrict__ kb, __bf16* __restrict__ vb,
    const float* __restrict__ bq, const float* __restrict__ bk,
    const float* __restrict__ bv) {
    __shared__ alignas(16) __bf16 As[128 * 32];
    __shared__ alignas(16) __bf16 Bs[128 * 32];
    const int t = threadIdx.x;
    const int wave = t >> 6, lane = t & 63;
    const int wr = wave >> 1, wc = wave & 1;
    const int lg = lane >> 4, lr = lane & 15;
    const int row0 = blockIdx.y * 128, col0 = blockIdx.x * 128;

    f32x4 acc[4][4];
#pragma unroll
    for (int i = 0; i < 4; i++)
#pragma unroll
        for (int j = 0; j < 4; j++) acc[i][j] = f32x4{0.f, 0.f, 0.f, 0.f};

    const int sr = t >> 2;          // 0..63 row within 64-row chunk
    const int sk = (t & 3) * 8;     // k element offset
    const __bf16* Ab = A + (size_t)(row0 + sr) * K + sk;
    const __bf16* Bb = BT + (size_t)(col0 + sr) * K + sk;

    for (int k0 = 0; k0 < K; k0 += 32) {
#pragma unroll
        for (int j = 0; j < 2; ++j) {
            gload_lds16(Ab + (size_t)j * 64 * K + k0, &As[(j * 256 + wave * 64) * 8]);
            gload_lds16(Bb + (size_t)j * 64 * K + k0, &Bs[(j * 256 + wave * 64) * 8]);
        }
        __syncthreads();
        bf16x8 af[4], bfm[4];
#pragma unroll
        for (int i = 0; i < 4; i++)
            af[i] = *(const bf16x8*)&As[(wr * 64 + i * 16 + lr) * 32 + lg * 8];
#pragma unroll
        for (int j = 0; j < 4; j++)
            bfm[j] = *(const bf16x8*)&Bs[(wc * 64 + j * 16 + lr) * 32 + lg * 8];
#pragma unroll
        for (int i = 0; i < 4; i++)
#pragma unroll
            for (int j = 0; j < 4; j++)
                acc[i][j] = __builtin_amdgcn_mfma_f32_16x16x32_bf16(
                    af[i], bfm[j], acc[i][j], 0, 0, 0);
        __syncthreads();
    }

#pragma unroll
    for (int i = 0; i < 4; i++) {
#pragma unroll
        for (int j = 0; j < 4; j++) {
#pragma unroll
            for (int r = 0; r < 4; r++) {
                const int row = row0 + wr * 64 + i * 16 + lg * 4 + r;
                const int col = col0 + wc * 64 + j * 16 + lr;
                float v = acc[i][j][r];
                if (MODE == 0) {
                    const int sec = col >> 10, cn = col & 1023;
                    const int head = cn >> 6, d = cn & 63;
                    if (sec == 0) {
                        v = (v + bq[cn]) * 0.125f;  // fold 1/sqrt(dk)
                        qb[((size_t)head * S_LEN + row) * DK + d] = (__bf16)v;
                    } else if (sec == 1) {
                        v = v + bk[cn];
                        kb[((size_t)head * S_LEN + row) * DK + d] = (__bf16)v;
                    } else {
                        v = v + bv[cn];
                        vb[((size_t)head * DK + d) * S_LEN + row] = (__bf16)v;  // V^T
                    }
                } else if (MODE == 1) {
                    const size_t idx = (size_t)row * N + col;
                    fout[idx] = fout[idx] + v + bias[col];
                } else if (MODE == 2) {
                    const float gg = v + bias[col];
                    const float c = 0.5f * gg * (1.0f + erff(gg * 0.70710678118654752f));
                    bfout[(size_t)row * N + col] = (__bf16)c;
                } else {
                    fout[(size_t)row * N + col] = v;
                }
            }
        }
    }
}

// ---------------------------------------------------------------------------
// Flash attention (causal). grid (S/64, NHEAD), block 256 (4 waves).
// Wave w handles q rows [qb*64 + w*16, +16).  KV tiles of 32.
// q,k layout [head][s][dk] bf16 (q pre-scaled); v layout [head][dk][s] bf16.
// Online softmax in f32; P -> bf16 via per-wave LDS repack.
// ---------------------------------------------------------------------------
__global__ __launch_bounds__(256) void attn_kernel(
    const __bf16* __restrict__ q, const __bf16* __restrict__ k,
    const __bf16* __restrict__ vt, __bf16* __restrict__ ctx) {
    const int qblk = blockIdx.x, head = blockIdx.y;
    const int t = threadIdx.x;
    const int wave = t >> 6, lane = t & 63;
    const int lg = lane >> 4, lr = lane & 15;
    const int rowbase = qblk * 64 + wave * 16;

    const __bf16* qh = q + (size_t)head * S_LEN * DK;
    const __bf16* kh = k + (size_t)head * S_LEN * DK;
    const __bf16* vh = vt + (size_t)head * DK * S_LEN;

    __shared__ alignas(16) __bf16 pls[4][16 * 32];
    __bf16* pw = pls[wave];

    bf16x8 qf0 = *(const bf16x8*)&qh[(size_t)(rowbase + lr) * DK + lg * 8];
    bf16x8 qf1 = *(const bf16x8*)&qh[(size_t)(rowbase + lr) * DK + 32 + lg * 8];

    f32x4 oacc[4];
#pragma unroll
    for (int j = 0; j < 4; j++) oacc[j] = f32x4{0.f, 0.f, 0.f, 0.f};
    float m[4], l[4];
#pragma unroll
    for (int r = 0; r < 4; r++) { m[r] = -__builtin_inff(); l[r] = 0.f; }

    const int tend = 2 * qblk + 1;  // uniform across waves (extra tiles fully masked)
    for (int tt = 0; tt <= tend; ++tt) {
        const int kv0 = tt * 32;
        f32x4 sc[2] = {f32x4{0.f, 0.f, 0.f, 0.f}, f32x4{0.f, 0.f, 0.f, 0.f}};
#pragma unroll
        for (int jn = 0; jn < 2; jn++) {
            bf16x8 kf0 = *(const bf16x8*)&kh[(size_t)(kv0 + jn * 16 + lr) * DK + lg * 8];
            bf16x8 kf1 = *(const bf16x8*)&kh[(size_t)(kv0 + jn * 16 + lr) * DK + 32 + lg * 8];
            sc[jn] = __builtin_amdgcn_mfma_f32_16x16x32_bf16(qf0, kf0, sc[jn], 0, 0, 0);
            sc[jn] = __builtin_amdgcn_mfma_f32_16x16x32_bf16(qf1, kf1, sc[jn], 0, 0, 0);
        }
        // causal mask + tile row max
        float mt[4];
#pragma unroll
        for (int r = 0; r < 4; r++) {
            const int qrow = rowbase + lg * 4 + r;
            if (kv0 + lr > qrow)      sc[0][r] = -__builtin_inff();
            if (kv0 + 16 + lr > qrow) sc[1][r] = -__builtin_inff();
            mt[r] = fmaxf(sc[0][r], sc[1][r]);
        }
#pragma unroll
        for (int off = 1; off < 16; off <<= 1)
#pragma unroll
            for (int r = 0; r < 4; r++) mt[r] = fmaxf(mt[r], __shfl_xor(mt[r], off));

        float alpha[4], psum[4];
#pragma unroll
        for (int r = 0; r < 4; r++) {
            const float mn = fmaxf(m[r], mt[r]);
            alpha[r] = expf(m[r] - mn);  // exp(-inf)=0 on first real tile
            m[r] = mn;
            sc[0][r] = expf(sc[0][r] - mn);
            sc[1][r] = expf(sc[1][r] - mn);
            psum[r] = sc[0][r] + sc[1][r];
        }
#pragma unroll
        for (int off = 1; off < 16; off <<= 1)
#pragma unroll
            for (int r = 0; r < 4; r++) psum[r] += __shfl_xor(psum[r], off);
#pragma unroll
        for (int r = 0; r < 4; r++) l[r] = l[r] * alpha[r] + psum[r];
#pragma unroll
        for (int j = 0; j < 4; j++)
#pragma unroll
            for (int r = 0; r < 4; r++) oacc[j][r] *= alpha[r];

        // repack P (D-layout) -> A-fragment layout via LDS
#pragma unroll
        for (int r = 0; r < 4; r++) {
            pw[(lg * 4 + r) * 32 + lr] = (__bf16)sc[0][r];
            pw[(lg * 4 + r) * 32 + 16 + lr] = (__bf16)sc[1][r];
        }
        __syncthreads();  // uniform trip count across waves -> legal
        bf16x8 pf = *(const bf16x8*)&pw[lr * 32 + lg * 8];
#pragma unroll
        for (int j = 0; j < 4; j++) {
            bf16x8 vf = *(const bf16x8*)&vh[(size_t)(j * 16 + lr) * S_LEN + kv0 + lg * 8];
            oacc[j] = __builtin_amdgcn_mfma_f32_16x16x32_bf16(pf, vf, oacc[j], 0, 0, 0);
        }
        __syncthreads();  // protect pls WAR before next iteration's writes
    }

#pragma unroll
    for (int j = 0; j < 4; j++)
#pragma unroll
        for (int r = 0; r < 4; r++) {
            const int row = rowbase + lg * 4 + r;
            ctx[(size_t)row * DMODEL + head * DK + j * 16 + lr] =
                (__bf16)(oacc[j][r] / l[r]);
        }
}

// ---------------------------------------------------------------------------
extern "C" void kernel_launch(void* const* d_in, const int* in_sizes, int n_in,
                              void* d_out, int out_size, void* d_ws, size_t ws_size,
                              hipStream_t stream) {
    const int*   tokens  = (const int*)d_in[0];
    const float* tok_emb = (const float*)d_in[1];
    const float* pos_emb = (const float*)d_in[2];
    const float* Wq = (const float*)d_in[3];
    const float* bq = (const float*)d_in[4];
    const float* Wk = (const float*)d_in[5];
    const float* bk = (const float*)d_in[6];
    const float* Wv = (const float*)d_in[7];
    const float* bv = (const float*)d_in[8];
    const float* Wo = (const float*)d_in[9];
    const float* bo = (const float*)d_in[10];
    const float* ln1_g = (const float*)d_in[11];
    const float* ln1_b = (const float*)d_in[12];
    const float* ln2_g = (const float*)d_in[13];
    const float* ln2_b = (const float*)d_in[14];
    const float* W1 = (const float*)d_in[15];
    const float* b1 = (const float*)d_in[16];
    const float* W2 = (const float*)d_in[17];
    const float* b2 = (const float*)d_in[18];
    const float* lnf_g = (const float*)d_in[19];
    const float* lnf_b = (const float*)d_in[20];

    // ---- workspace layout -------------------------------------------------
    char* ws = (char*)d_ws;
    size_t off = 0;
    auto alloc = [&](size_t bytes) {
        char* p = ws + off;
        off = (off + bytes + 255) & ~(size_t)255;
        return p;
    };
    __bf16* wqkv_t = (__bf16*)alloc((size_t)NLAYER * 3072 * 1024 * 2);
    __bf16* wo_t   = (__bf16*)alloc((size_t)NLAYER * 1024 * 1024 * 2);
    __bf16* w1_t   = (__bf16*)alloc((size_t)NLAYER * 4096 * 1024 * 2);
    __bf16* w2_t   = (__bf16*)alloc((size_t)NLAYER * 1024 * 4096 * 2);
    __bf16* temb   = (__bf16*)alloc((size_t)VOCAB * DMODEL * 2);
    float*  x      = (float*)alloc((size_t)S_LEN * DMODEL * 4);
    __bf16* h      = (__bf16*)alloc((size_t)S_LEN * DMODEL * 2);
    __bf16* qbuf   = (__bf16*)alloc((size_t)NHEAD * S_LEN * DK * 2);
    __bf16* kbuf   = (__bf16*)alloc((size_t)NHEAD * S_LEN * DK * 2);
    __bf16* vbuf   = (__bf16*)alloc((size_t)NHEAD * S_LEN * DK * 2);
    __bf16* ctx    = (__bf16*)alloc((size_t)S_LEN * DMODEL * 2);
    __bf16* ffn    = (__bf16*)alloc((size_t)S_LEN * DFF * 2);
    if (off > ws_size) return;  // loud failure: leaves poison in d_out

    const dim3 blk256(256);
    const dim3 tblk(32, 8);

    // ---- weight prep (every call; deterministic) --------------------------
    for (int l = 0; l < NLAYER; ++l) {
        const size_t dd = (size_t)l * 1024 * 1024;
        transpose_cvt<<<dim3(32, 32), tblk, 0, stream>>>(
            Wq + dd, wqkv_t + (size_t)l * 3072 * 1024, 1024, 1024);
        transpose_cvt<<<dim3(32, 32), tblk, 0, stream>>>(
            Wk + dd, wqkv_t + (size_t)l * 3072 * 1024 + 1024 * 1024, 1024, 1024);
        transpose_cvt<<<dim3(32, 32), tblk, 0, stream>>>(
            Wv + dd, wqkv_t + (size_t)l * 3072 * 1024 + 2 * 1024 * 1024, 1024, 1024);
        transpose_cvt<<<dim3(32, 32), tblk, 0, stream>>>(
            Wo + dd, wo_t + (size_t)l * 1024 * 1024, 1024, 1024);
        transpose_cvt<<<dim3(128, 32), tblk, 0, stream>>>(
            W1 + (size_t)l * 1024 * 4096, w1_t + (size_t)l * 4096 * 1024, 1024, 4096);
        transpose_cvt<<<dim3(32, 128), tblk, 0, stream>>>(
            W2 + (size_t)l * 4096 * 1024, w2_t + (size_t)l * 1024 * 4096, 4096, 1024);
    }
    cvt_bf16<<<dim3((VOCAB * DMODEL / 4 + 255) / 256), blk256, 0, stream>>>(
        tok_emb, temb, (long)VOCAB * DMODEL / 4);

    // ---- embedding --------------------------------------------------------
    embed_kernel<<<dim3(S_LEN), blk256, 0, stream>>>(tokens, tok_emb, pos_emb, x);

    // ---- transformer blocks ----------------------------------------------
    for (int l = 0; l < NLAYER; ++l) {
        ln_kernel<<<dim3(S_LEN), blk256, 0, stream>>>(
            x, ln1_g + l * 1024, ln1_b + l * 1024, h);
        gemm_kernel<0><<<dim3(24, 16), blk256, 0, stream>>>(
            h, wqkv_t + (size_t)l * 3072 * 1024, S_LEN, 3072, 1024,
            nullptr, nullptr, nullptr, qbuf, kbuf, vbuf,
            bq + l * 1024, bk + l * 1024, bv + l * 1024);
        attn_kernel<<<dim3(S_LEN / 64, NHEAD), blk256, 0, stream>>>(
            qbuf, kbuf, vbuf, ctx);
        gemm_kernel<1><<<dim3(8, 16), blk256, 0, stream>>>(
            ctx, wo_t + (size_t)l * 1024 * 1024, S_LEN, 1024, 1024,
            bo + l * 1024, x, nullptr, nullptr, nullptr, nullptr,
            nullptr, nullptr, nullptr);
        ln_kernel<<<dim3(S_LEN), blk256, 0, stream>>>(
            x, ln2_g + l * 1024, ln2_b + l * 1024, h);
        gemm_kernel<2><<<dim3(32, 16), blk256, 0, stream>>>(
            h, w1_t + (size_t)l * 4096 * 1024, S_LEN, 4096, 1024,
            b1 + l * 4096, nullptr, ffn, nullptr, nullptr, nullptr,
            nullptr, nullptr, nullptr);
        gemm_kernel<1><<<dim3(8, 16), blk256, 0, stream>>>(
            ffn, w2_t + (size_t)l * 1024 * 4096, S_LEN, 1024, 4096,
            b2 + l * 1024, x, nullptr, nullptr, nullptr, nullptr,
            nullptr, nullptr, nullptr);
    }

    // ---- final LN + tied-logits GEMM -------------------------------------
    ln_kernel<<<dim3(S_LEN), blk256, 0, stream>>>(x, lnf_g, lnf_b, h);
    gemm_kernel<3><<<dim3(VOCAB / 128, 16), blk256, 0, stream>>>(
        h, temb, S_LEN, VOCAB, 1024,
        nullptr, (float*)d_out, nullptr, nullptr, nullptr, nullptr,
        nullptr, nullptr, nullptr);
}

// Round 2
// 2423.385 us; speedup vs baseline: 1.2265x; 1.2265x over previous
//
#include <hip/hip_runtime.h>
#include <hip/hip_bf16.h>
#include <cstdint>
#include <cstddef>

// ---------------------------------------------------------------------------
// MiniGPT forward on MI355X (gfx950).  Round 1:
//  - GEMMs: explicit LDS double-buffer + counted vmcnt (no barrier drain),
//    XOR-swizzled LDS (conflict-free ds_read_b128), both-sides swizzle with
//    pre-swizzled global_load_lds source (rule 21).
//  - logits GEMM: new 256x256 BK=64 8-wave kernel, XCD-swizzled grid,
//    nontemporal f32 stores.
//  - attention: no __syncthreads (per-wave P buffer), wave-exact trip count,
//    __expf, setprio around MFMA.
// ---------------------------------------------------------------------------

typedef __attribute__((ext_vector_type(4))) float  f32x4;
typedef __attribute__((ext_vector_type(8))) __bf16 bf16x8;
typedef __attribute__((ext_vector_type(4))) __bf16 bf16x4;

#define S_LEN 2048
#define DMODEL 1024
#define DFF 4096
#define NLAYER 6
#define NHEAD 16
#define DK 64
#define VOCAB 32000

__device__ __forceinline__ void gload_lds16(const void* g, void* l) {
    __builtin_amdgcn_global_load_lds(
        (__attribute__((address_space(1))) void*)(void*)(g),
        (__attribute__((address_space(3))) void*)(l), 16, 0, 0);
}

// ---------------------------------------------------------------------------
// transpose + f32->bf16:  in[K][N] (f32) -> out[N][K] (bf16)
// ---------------------------------------------------------------------------
__global__ __launch_bounds__(256) void transpose_cvt(
    const float* __restrict__ in, __bf16* __restrict__ out, int K, int N) {
    __shared__ float tile[32][33];
    const int n0 = blockIdx.x * 32, k0 = blockIdx.y * 32;
    const int tx = threadIdx.x, ty = threadIdx.y;
#pragma unroll
    for (int j = 0; j < 32; j += 8)
        tile[ty + j][tx] = in[(size_t)(k0 + ty + j) * N + (n0 + tx)];
    __syncthreads();
#pragma unroll
    for (int j = 0; j < 32; j += 8)
        out[(size_t)(n0 + ty + j) * K + (k0 + tx)] = (__bf16)tile[tx][ty + j];
}

__global__ __launch_bounds__(256) void cvt_bf16(
    const float* __restrict__ in, __bf16* __restrict__ out, long n4) {
    long i = (long)blockIdx.x * 256 + threadIdx.x;
    if (i >= n4) return;
    float4 v = ((const float4*)in)[i];
    bf16x4 o = {(__bf16)v.x, (__bf16)v.y, (__bf16)v.z, (__bf16)v.w};
    ((bf16x4*)out)[i] = o;
}

__global__ __launch_bounds__(256) void embed_kernel(
    const int* __restrict__ tokens, const float* __restrict__ te,
    const float* __restrict__ pe, float* __restrict__ x) {
    const int s = blockIdx.x, t = threadIdx.x;
    const int tok = tokens[s];
    float4 a = ((const float4*)(te + (size_t)tok * DMODEL))[t];
    float4 p = ((const float4*)(pe + (size_t)s * DMODEL))[t];
    float4 r = {a.x + p.x, a.y + p.y, a.z + p.z, a.w + p.w};
    ((float4*)(x + (size_t)s * DMODEL))[t] = r;
}

__global__ __launch_bounds__(256) void ln_kernel(
    const float* __restrict__ x, const float* __restrict__ g,
    const float* __restrict__ b, __bf16* __restrict__ out) {
    const int row = blockIdx.x, t = threadIdx.x;
    float4 v = ((const float4*)(x + (size_t)row * DMODEL))[t];
    float s  = v.x + v.y + v.z + v.w;
    float s2 = v.x * v.x + v.y * v.y + v.z * v.z + v.w * v.w;
#pragma unroll
    for (int off = 1; off < 64; off <<= 1) {
        s  += __shfl_xor(s, off);
        s2 += __shfl_xor(s2, off);
    }
    __shared__ float ss[4], ss2[4];
    const int wave = t >> 6;
    if ((t & 63) == 0) { ss[wave] = s; ss2[wave] = s2; }
    __syncthreads();
    s  = ss[0] + ss[1] + ss[2] + ss[3];
    s2 = ss2[0] + ss2[1] + ss2[2] + ss2[3];
    const float mu  = s * (1.0f / DMODEL);
    const float var = s2 * (1.0f / DMODEL) - mu * mu;
    const float rstd = rsqrtf(var + 1e-5f);
    float4 gg = ((const float4*)g)[t];
    float4 bb = ((const float4*)b)[t];
    __bf16* o = out + (size_t)row * DMODEL + t * 4;
    o[0] = (__bf16)((v.x - mu) * rstd * gg.x + bb.x);
    o[1] = (__bf16)((v.y - mu) * rstd * gg.y + bb.y);
    o[2] = (__bf16)((v.z - mu) * rstd * gg.z + bb.z);
    o[3] = (__bf16)((v.w - mu) * rstd * gg.w + bb.w);
}

// ---------------------------------------------------------------------------
// 128x128 GEMM, BK=32, 4 waves.  LDS dbuf + counted vmcnt + XOR swizzle.
//   logical LDS tile: [row][32 k-elems] (64B rows = 4x 16B slots)
//   physical slot = logical slot ^ (row & 3); source pre-swizzled to match.
// MODE 0: QKV split  MODE 1: residual+=  MODE 2: GELU->bf16  MODE 3: f32 store
// ---------------------------------------------------------------------------
template <int MODE>
__global__ __launch_bounds__(256) void gemm_kernel(
    const __bf16* __restrict__ A, const __bf16* __restrict__ BT,
    int M, int N, int K,
    const float* __restrict__ bias,
    float* __restrict__ fout,
    __bf16* __restrict__ bfout,
    __bf16* __restrict__ qb, __bf16* __restrict__ kb, __bf16* __restrict__ vb,
    const float* __restrict__ bq, const float* __restrict__ bk,
    const float* __restrict__ bv) {
    __shared__ alignas(16) __bf16 lds[2][2][128 * 32];  // [buf][A/B]
    const int t = threadIdx.x;
    const int wave = t >> 6, lane = t & 63;
    const int wr = wave >> 1, wc = wave & 1;
    const int lg = lane >> 4, lr = lane & 15;
    const int row0 = blockIdx.y * 128, col0 = blockIdx.x * 128;

    f32x4 acc[4][4];
#pragma unroll
    for (int i = 0; i < 4; i++)
#pragma unroll
        for (int j = 0; j < 4; j++) acc[i][j] = f32x4{0.f, 0.f, 0.f, 0.f};

    const int sr = t >> 2;                               // staging row 0..63
    const int sks = (((t & 3) ^ (sr & 3))) * 8;          // pre-swizzled k src
    const __bf16* Ab = A + (size_t)(row0 + sr) * K + sks;
    const __bf16* Bb = BT + (size_t)(col0 + sr) * K + sks;

    const int nt = K >> 5;
    // prologue: stage tile 0 into buf 0
#pragma unroll
    for (int j = 0; j < 2; ++j) {
        gload_lds16(Ab + (size_t)j * 64 * K, &lds[0][0][(j * 64 + wave * 16) * 32]);
        gload_lds16(Bb + (size_t)j * 64 * K, &lds[0][1][(j * 64 + wave * 16) * 32]);
    }
    int c = 0;
    for (int ks = 0; ks < nt; ++ks) {
        if (ks + 1 < nt) {
            const int k0 = (ks + 1) << 5;
#pragma unroll
            for (int j = 0; j < 2; ++j) {
                gload_lds16(Ab + (size_t)j * 64 * K + k0,
                            &lds[c ^ 1][0][(j * 64 + wave * 16) * 32]);
                gload_lds16(Bb + (size_t)j * 64 * K + k0,
                            &lds[c ^ 1][1][(j * 64 + wave * 16) * 32]);
            }
            asm volatile("s_waitcnt vmcnt(4)" ::: "memory");
        } else {
            asm volatile("s_waitcnt vmcnt(0)" ::: "memory");
        }
        __builtin_amdgcn_s_barrier();
        asm volatile("" ::: "memory");

        const __bf16* As = lds[c][0];
        const __bf16* Bs = lds[c][1];
        const int swz = (lg ^ (lr & 3)) * 8;
        bf16x8 af[4], bfm[4];
#pragma unroll
        for (int i = 0; i < 4; i++)
            af[i] = *(const bf16x8*)&As[(wr * 64 + i * 16 + lr) * 32 + swz];
#pragma unroll
        for (int j = 0; j < 4; j++)
            bfm[j] = *(const bf16x8*)&Bs[(wc * 64 + j * 16 + lr) * 32 + swz];
        __builtin_amdgcn_s_setprio(1);
#pragma unroll
        for (int i = 0; i < 4; i++)
#pragma unroll
            for (int j = 0; j < 4; j++)
                acc[i][j] = __builtin_amdgcn_mfma_f32_16x16x32_bf16(
                    af[i], bfm[j], acc[i][j], 0, 0, 0);
        __builtin_amdgcn_s_setprio(0);
        asm volatile("" ::: "memory");
        __builtin_amdgcn_s_barrier();   // all reads of buf c done -> next stage may overwrite
        c ^= 1;
    }

#pragma unroll
    for (int i = 0; i < 4; i++) {
#pragma unroll
        for (int j = 0; j < 4; j++) {
#pragma unroll
            for (int r = 0; r < 4; r++) {
                const int row = row0 + wr * 64 + i * 16 + lg * 4 + r;
                const int col = col0 + wc * 64 + j * 16 + lr;
                float v = acc[i][j][r];
                if (MODE == 0) {
                    const int sec = col >> 10, cn = col & 1023;
                    const int head = cn >> 6, d = cn & 63;
                    if (sec == 0) {
                        v = (v + bq[cn]) * 0.125f;
                        qb[((size_t)head * S_LEN + row) * DK + d] = (__bf16)v;
                    } else if (sec == 1) {
                        v = v + bk[cn];
                        kb[((size_t)head * S_LEN + row) * DK + d] = (__bf16)v;
                    } else {
                        v = v + bv[cn];
                        vb[((size_t)head * DK + d) * S_LEN + row] = (__bf16)v;
                    }
                } else if (MODE == 1) {
                    const size_t idx = (size_t)row * N + col;
                    fout[idx] = fout[idx] + v + bias[col];
                } else if (MODE == 2) {
                    const float gg = v + bias[col];
                    const float cgl = 0.5f * gg * (1.0f + erff(gg * 0.70710678118654752f));
                    bfout[(size_t)row * N + col] = (__bf16)cgl;
                } else {
                    fout[(size_t)row * N + col] = v;
                }
            }
        }
    }
}

// ---------------------------------------------------------------------------
// 256x256 GEMM, BK=64, 8 waves (2M x 4N), 128 KiB LDS dbuf, counted vmcnt,
// XOR swizzle (slot ^= row&7), XCD-swizzled 1-D grid, nontemporal f32 store.
// Requires M%256==0, N%256==0, K%64==0, gridDim.x == (M/256)*(N/256), %8==0.
// ---------------------------------------------------------------------------
__global__ __launch_bounds__(512, 2) void gemm256_kernel(
    const __bf16* __restrict__ A, const __bf16* __restrict__ BT,
    int M, int N, int K, int mblocks, float* __restrict__ fout) {
    __shared__ alignas(16) __bf16 lds[2][2][256 * 64];  // 128 KiB
    const int t = threadIdx.x;
    const int wv = t >> 6, lane = t & 63;
    const int wm = wv >> 2, wn = wv & 3;
    const int lg = lane >> 4, lr = lane & 15;

    // bijective XCD swizzle (nwg % 8 == 0)
    const int nwg = gridDim.x;
    const int sw = (blockIdx.x & 7) * (nwg >> 3) + (blockIdx.x >> 3);
    const int row0 = (sw % mblocks) * 256;
    const int col0 = (sw / mblocks) * 256;

    f32x4 acc[8][4];
#pragma unroll
    for (int i = 0; i < 8; i++)
#pragma unroll
        for (int j = 0; j < 4; j++) acc[i][j] = f32x4{0.f, 0.f, 0.f, 0.f};

    const int strow = t >> 3;                              // 0..63
    const int sks = ((t & 7) ^ (strow & 7)) * 8;           // pre-swizzled k src
    const __bf16* Ab = A + (size_t)(row0 + strow) * K + sks;
    const __bf16* Bb = BT + (size_t)(col0 + strow) * K + sks;

    const int nt = K >> 6;
    // prologue: stage tile 0 into buf 0
#pragma unroll
    for (int ch = 0; ch < 4; ++ch) {
        gload_lds16(Ab + (size_t)ch * 64 * K, &lds[0][0][(ch * 64 + wv * 8) * 64]);
        gload_lds16(Bb + (size_t)ch * 64 * K, &lds[0][1][(ch * 64 + wv * 8) * 64]);
    }
    int c = 0;
    for (int T = 0; T < nt; ++T) {
        if (T + 1 < nt) {
            const int k0 = (T + 1) << 6;
#pragma unroll
            for (int ch = 0; ch < 4; ++ch) {
                gload_lds16(Ab + (size_t)ch * 64 * K + k0,
                            &lds[c ^ 1][0][(ch * 64 + wv * 8) * 64]);
                gload_lds16(Bb + (size_t)ch * 64 * K + k0,
                            &lds[c ^ 1][1][(ch * 64 + wv * 8) * 64]);
            }
            asm volatile("s_waitcnt vmcnt(8)" ::: "memory");
        } else {
            asm volatile("s_waitcnt vmcnt(0)" ::: "memory");
        }
        __builtin_amdgcn_s_barrier();
        asm volatile("" ::: "memory");

        const __bf16* As = lds[c][0];
        const __bf16* Bs = lds[c][1];
#pragma unroll
        for (int mq = 0; mq < 2; ++mq) {
            bf16x8 af[4][2];
#pragma unroll
            for (int i = 0; i < 4; i++)
#pragma unroll
                for (int ks = 0; ks < 2; ks++) {
                    const int row = wm * 128 + mq * 64 + i * 16 + lr;
                    af[i][ks] = *(const bf16x8*)
                        &As[row * 64 + (((ks * 4 + lg) ^ (row & 7)) * 8)];
                }
#pragma unroll
            for (int nq = 0; nq < 2; ++nq) {
                bf16x8 bfr[2][2];
#pragma unroll
                for (int j = 0; j < 2; j++)
#pragma unroll
                    for (int ks = 0; ks < 2; ks++) {
                        const int n = wn * 64 + nq * 32 + j * 16 + lr;
                        bfr[j][ks] = *(const bf16x8*)
                            &Bs[n * 64 + (((ks * 4 + lg) ^ (n & 7)) * 8)];
                    }
                __builtin_amdgcn_s_setprio(1);
#pragma unroll
                for (int i = 0; i < 4; i++)
#pragma unroll
                    for (int j = 0; j < 2; j++)
#pragma unroll
                        for (int ks = 0; ks < 2; ks++)
                            acc[mq * 4 + i][nq * 2 + j] =
                                __builtin_amdgcn_mfma_f32_16x16x32_bf16(
                                    af[i][ks], bfr[j][ks],
                                    acc[mq * 4 + i][nq * 2 + j], 0, 0, 0);
                __builtin_amdgcn_s_setprio(0);
            }
        }
        asm volatile("" ::: "memory");
        __builtin_amdgcn_s_barrier();
        c ^= 1;
    }

#pragma unroll
    for (int i = 0; i < 8; i++)
#pragma unroll
        for (int j = 0; j < 4; j++)
#pragma unroll
            for (int r = 0; r < 4; r++) {
                const int row = row0 + wm * 128 + i * 16 + lg * 4 + r;
                const int col = col0 + wn * 64 + j * 16 + lr;
                __builtin_nontemporal_store(acc[i][j][r],
                                            &fout[(size_t)row * N + col]);
            }
}

// ---------------------------------------------------------------------------
// Flash attention (causal). grid (S/64, NHEAD), block 256 (4 waves).
// No __syncthreads: P repack buffer is per-wave; waves fully independent.
// ---------------------------------------------------------------------------
__global__ __launch_bounds__(256) void attn_kernel(
    const __bf16* __restrict__ q, const __bf16* __restrict__ k,
    const __bf16* __restrict__ vt, __bf16* __restrict__ ctx) {
    const int qblk = blockIdx.x, head = blockIdx.y;
    const int t = threadIdx.x;
    const int wave = t >> 6, lane = t & 63;
    const int lg = lane >> 4, lr = lane & 15;
    const int rowbase = qblk * 64 + wave * 16;

    const __bf16* qh = q + (size_t)head * S_LEN * DK;
    const __bf16* kh = k + (size_t)head * S_LEN * DK;
    const __bf16* vh = vt + (size_t)head * DK * S_LEN;

    __shared__ alignas(16) __bf16 pls[4][16 * 32];
    __bf16* pw = pls[wave];

    bf16x8 qf0 = *(const bf16x8*)&qh[(size_t)(rowbase + lr) * DK + lg * 8];
    bf16x8 qf1 = *(const bf16x8*)&qh[(size_t)(rowbase + lr) * DK + 32 + lg * 8];

    f32x4 oacc[4];
#pragma unroll
    for (int j = 0; j < 4; j++) oacc[j] = f32x4{0.f, 0.f, 0.f, 0.f};
    float m[4], l[4];
#pragma unroll
    for (int r = 0; r < 4; r++) { m[r] = -__builtin_inff(); l[r] = 0.f; }

    const int tend = 2 * qblk + (wave >= 2 ? 1 : 0);  // wave-exact (no barriers)
    for (int tt = 0; tt <= tend; ++tt) {
        const int kv0 = tt * 32;
        f32x4 sc[2] = {f32x4{0.f, 0.f, 0.f, 0.f}, f32x4{0.f, 0.f, 0.f, 0.f}};
        __builtin_amdgcn_s_setprio(1);
#pragma unroll
        for (int jn = 0; jn < 2; jn++) {
            bf16x8 kf0 = *(const bf16x8*)&kh[(size_t)(kv0 + jn * 16 + lr) * DK + lg * 8];
            bf16x8 kf1 = *(const bf16x8*)&kh[(size_t)(kv0 + jn * 16 + lr) * DK + 32 + lg * 8];
            sc[jn] = __builtin_amdgcn_mfma_f32_16x16x32_bf16(qf0, kf0, sc[jn], 0, 0, 0);
            sc[jn] = __builtin_amdgcn_mfma_f32_16x16x32_bf16(qf1, kf1, sc[jn], 0, 0, 0);
        }
        __builtin_amdgcn_s_setprio(0);
        float mt[4];
#pragma unroll
        for (int r = 0; r < 4; r++) {
            const int qrow = rowbase + lg * 4 + r;
            if (kv0 + lr > qrow)      sc[0][r] = -__builtin_inff();
            if (kv0 + 16 + lr > qrow) sc[1][r] = -__builtin_inff();
            mt[r] = fmaxf(sc[0][r], sc[1][r]);
        }
#pragma unroll
        for (int off = 1; off < 16; off <<= 1)
#pragma unroll
            for (int r = 0; r < 4; r++) mt[r] = fmaxf(mt[r], __shfl_xor(mt[r], off));

        float alpha[4], psum[4];
#pragma unroll
        for (int r = 0; r < 4; r++) {
            const float mn = fmaxf(m[r], mt[r]);
            alpha[r] = __expf(m[r] - mn);
            m[r] = mn;
            sc[0][r] = __expf(sc[0][r] - mn);
            sc[1][r] = __expf(sc[1][r] - mn);
            psum[r] = sc[0][r] + sc[1][r];
        }
#pragma unroll
        for (int off = 1; off < 16; off <<= 1)
#pragma unroll
            for (int r = 0; r < 4; r++) psum[r] += __shfl_xor(psum[r], off);
#pragma unroll
        for (int r = 0; r < 4; r++) l[r] = l[r] * alpha[r] + psum[r];
#pragma unroll
        for (int j = 0; j < 4; j++)
#pragma unroll
            for (int r = 0; r < 4; r++) oacc[j][r] *= alpha[r];

        // repack P (D-layout) -> A-fragment layout via per-wave LDS
#pragma unroll
        for (int r = 0; r < 4; r++) {
            pw[(lg * 4 + r) * 32 + lr] = (__bf16)sc[0][r];
            pw[(lg * 4 + r) * 32 + 16 + lr] = (__bf16)sc[1][r];
        }
        bf16x8 pf = *(const bf16x8*)&pw[lr * 32 + lg * 8];
        __builtin_amdgcn_s_setprio(1);
#pragma unroll
        for (int j = 0; j < 4; j++) {
            bf16x8 vf = *(const bf16x8*)&vh[(size_t)(j * 16 + lr) * S_LEN + kv0 + lg * 8];
            oacc[j] = __builtin_amdgcn_mfma_f32_16x16x32_bf16(pf, vf, oacc[j], 0, 0, 0);
        }
        __builtin_amdgcn_s_setprio(0);
    }

#pragma unroll
    for (int j = 0; j < 4; j++)
#pragma unroll
        for (int r = 0; r < 4; r++) {
            const int row = rowbase + lg * 4 + r;
            ctx[(size_t)row * DMODEL + head * DK + j * 16 + lr] =
                (__bf16)(oacc[j][r] / l[r]);
        }
}

// ---------------------------------------------------------------------------
extern "C" void kernel_launch(void* const* d_in, const int* in_sizes, int n_in,
                              void* d_out, int out_size, void* d_ws, size_t ws_size,
                              hipStream_t stream) {
    const int*   tokens  = (const int*)d_in[0];
    const float* tok_emb = (const float*)d_in[1];
    const float* pos_emb = (const float*)d_in[2];
    const float* Wq = (const float*)d_in[3];
    const float* bq = (const float*)d_in[4];
    const float* Wk = (const float*)d_in[5];
    const float* bk = (const float*)d_in[6];
    const float* Wv = (const float*)d_in[7];
    const float* bv = (const float*)d_in[8];
    const float* Wo = (const float*)d_in[9];
    const float* bo = (const float*)d_in[10];
    const float* ln1_g = (const float*)d_in[11];
    const float* ln1_b = (const float*)d_in[12];
    const float* ln2_g = (const float*)d_in[13];
    const float* ln2_b = (const float*)d_in[14];
    const float* W1 = (const float*)d_in[15];
    const float* b1 = (const float*)d_in[16];
    const float* W2 = (const float*)d_in[17];
    const float* b2 = (const float*)d_in[18];
    const float* lnf_g = (const float*)d_in[19];
    const float* lnf_b = (const float*)d_in[20];

    char* ws = (char*)d_ws;
    size_t off = 0;
    auto alloc = [&](size_t bytes) {
        char* p = ws + off;
        off = (off + bytes + 255) & ~(size_t)255;
        return p;
    };
    __bf16* wqkv_t = (__bf16*)alloc((size_t)NLAYER * 3072 * 1024 * 2);
    __bf16* wo_t   = (__bf16*)alloc((size_t)NLAYER * 1024 * 1024 * 2);
    __bf16* w1_t   = (__bf16*)alloc((size_t)NLAYER * 4096 * 1024 * 2);
    __bf16* w2_t   = (__bf16*)alloc((size_t)NLAYER * 1024 * 4096 * 2);
    __bf16* temb   = (__bf16*)alloc((size_t)VOCAB * DMODEL * 2);
    float*  x      = (float*)alloc((size_t)S_LEN * DMODEL * 4);
    __bf16* h      = (__bf16*)alloc((size_t)S_LEN * DMODEL * 2);
    __bf16* qbuf   = (__bf16*)alloc((size_t)NHEAD * S_LEN * DK * 2);
    __bf16* kbuf   = (__bf16*)alloc((size_t)NHEAD * S_LEN * DK * 2);
    __bf16* vbuf   = (__bf16*)alloc((size_t)NHEAD * S_LEN * DK * 2);
    __bf16* ctx    = (__bf16*)alloc((size_t)S_LEN * DMODEL * 2);
    __bf16* ffn    = (__bf16*)alloc((size_t)S_LEN * DFF * 2);
    if (off > ws_size) return;

    const dim3 blk256(256);
    const dim3 tblk(32, 8);

    for (int l = 0; l < NLAYER; ++l) {
        const size_t dd = (size_t)l * 1024 * 1024;
        transpose_cvt<<<dim3(32, 32), tblk, 0, stream>>>(
            Wq + dd, wqkv_t + (size_t)l * 3072 * 1024, 1024, 1024);
        transpose_cvt<<<dim3(32, 32), tblk, 0, stream>>>(
            Wk + dd, wqkv_t + (size_t)l * 3072 * 1024 + 1024 * 1024, 1024, 1024);
        transpose_cvt<<<dim3(32, 32), tblk, 0, stream>>>(
            Wv + dd, wqkv_t + (size_t)l * 3072 * 1024 + 2 * 1024 * 1024, 1024, 1024);
        transpose_cvt<<<dim3(32, 32), tblk, 0, stream>>>(
            Wo + dd, wo_t + (size_t)l * 1024 * 1024, 1024, 1024);
        transpose_cvt<<<dim3(128, 32), tblk, 0, stream>>>(
            W1 + (size_t)l * 1024 * 4096, w1_t + (size_t)l * 4096 * 1024, 1024, 4096);
        transpose_cvt<<<dim3(32, 128), tblk, 0, stream>>>(
            W2 + (size_t)l * 4096 * 1024, w2_t + (size_t)l * 1024 * 4096, 4096, 1024);
    }
    cvt_bf16<<<dim3((VOCAB * DMODEL / 4 + 255) / 256), blk256, 0, stream>>>(
        tok_emb, temb, (long)VOCAB * DMODEL / 4);

    embed_kernel<<<dim3(S_LEN), blk256, 0, stream>>>(tokens, tok_emb, pos_emb, x);

    for (int l = 0; l < NLAYER; ++l) {
        ln_kernel<<<dim3(S_LEN), blk256, 0, stream>>>(
            x, ln1_g + l * 1024, ln1_b + l * 1024, h);
        gemm_kernel<0><<<dim3(24, 16), blk256, 0, stream>>>(
            h, wqkv_t + (size_t)l * 3072 * 1024, S_LEN, 3072, 1024,
            nullptr, nullptr, nullptr, qbuf, kbuf, vbuf,
            bq + l * 1024, bk + l * 1024, bv + l * 1024);
        attn_kernel<<<dim3(S_LEN / 64, NHEAD), blk256, 0, stream>>>(
            qbuf, kbuf, vbuf, ctx);
        gemm_kernel<1><<<dim3(8, 16), blk256, 0, stream>>>(
            ctx, wo_t + (size_t)l * 1024 * 1024, S_LEN, 1024, 1024,
            bo + l * 1024, x, nullptr, nullptr, nullptr, nullptr,
            nullptr, nullptr, nullptr);
        ln_kernel<<<dim3(S_LEN), blk256, 0, stream>>>(
            x, ln2_g + l * 1024, ln2_b + l * 1024, h);
        gemm_kernel<2><<<dim3(32, 16), blk256, 0, stream>>>(
            h, w1_t + (size_t)l * 4096 * 1024, S_LEN, 4096, 1024,
            b1 + l * 4096, nullptr, ffn, nullptr, nullptr, nullptr,
            nullptr, nullptr, nullptr);
        gemm_kernel<1><<<dim3(8, 16), blk256, 0, stream>>>(
            ffn, w2_t + (size_t)l * 1024 * 4096, S_LEN, 1024, 4096,
            b2 + l * 1024, x, nullptr, nullptr, nullptr, nullptr,
            nullptr, nullptr, nullptr);
    }

    ln_kernel<<<dim3(S_LEN), blk256, 0, stream>>>(x, lnf_g, lnf_b, h);
    // logits: M=2048 (8 row-blocks), N=32000 (125 col-blocks) -> 1000 WGs
    gemm256_kernel<<<dim3(1000), dim3(512), 0, stream>>>(
        h, temb, S_LEN, VOCAB, 1024, 8, (float*)d_out);
}